// Round 3
// baseline (492.951 us; speedup 1.0000x reference)
//
#include <hip/hip_runtime.h>
#include <hip/hip_bf16.h>

// NATLayer fp32 I/O, bf16 internal compute. B=8, H=W=128, C=128, HEADS=4,
// d=32, KSIZE=7, N=16384 (1-D neighborhood over flattened N), M = B*N = 131072.
//
// Round 3: (a) nat_attn rewritten thread-per-(token,head) with LDS-staged K/V
// (removes 11x VALU inflation of shuffle-reduce); (b) GEMM grid swapped so
// n is fastest -> consecutive blocks share the A-tile via L2/L3.

#define NPOS 16384
#define MROWS 131072
#define CHUNK 65536            // rows per chunk (multiple of NPOS)

typedef unsigned short ushort_t;
typedef __bf16 bf8 __attribute__((ext_vector_type(8)));
typedef float f4 __attribute__((ext_vector_type(4)));

// param block offsets (bf16 elems)
#define P_QKV_W 0
#define P_QKV_B 49152
#define P_PROJ_W 49536
#define P_PROJ_B 65920
#define P_FC1_W 66048
#define P_FC1_B 131584
#define P_FC2_W 132096
#define P_FC2_B 197632
#define P_TOTAL 197760

__device__ __forceinline__ float b2f(ushort_t u) {
    union { unsigned int i; float f; } v; v.i = ((unsigned int)u) << 16; return v.f;
}
__device__ __forceinline__ ushort_t f2b(float f) {
    __hip_bfloat16 h = __float2bfloat16(f);
    return *reinterpret_cast<ushort_t*>(&h);
}

// ---------------- fp32 -> bf16 weight conversion (one launch) ---------------
__global__ __launch_bounds__(256) void cvt_params(
    const float* __restrict__ qkv_w, const float* __restrict__ qkv_b,
    const float* __restrict__ proj_w, const float* __restrict__ proj_b,
    const float* __restrict__ fc1_w, const float* __restrict__ fc1_b,
    const float* __restrict__ fc2_w, const float* __restrict__ fc2_b,
    ushort_t* __restrict__ p)
{
    int i = blockIdx.x * 256 + threadIdx.x;
    if (i >= P_TOTAL) return;
    float v;
    if      (i < P_QKV_B)  v = qkv_w[i - P_QKV_W];
    else if (i < P_PROJ_W) v = qkv_b[i - P_QKV_B];
    else if (i < P_PROJ_B) v = proj_w[i - P_PROJ_W];
    else if (i < P_FC1_W)  v = proj_b[i - P_PROJ_B];
    else if (i < P_FC1_B)  v = fc1_w[i - P_FC1_W];
    else if (i < P_FC2_W)  v = fc1_b[i - P_FC1_B];
    else if (i < P_FC2_B)  v = fc2_w[i - P_FC2_W];
    else                   v = fc2_b[i - P_FC2_B];
    p[i] = f2b(v);
}

// ---------------- LayerNorm over C=128, one wave per row, out bf16 ----------
template<typename T>
__global__ __launch_bounds__(256) void ln_kernel(
    const T* __restrict__ x, const float* __restrict__ w,
    const float* __restrict__ b, ushort_t* __restrict__ out)
{
    int row  = blockIdx.x * 4 + (threadIdx.x >> 6);
    int lane = threadIdx.x & 63;
    int c0 = lane * 2;
    float v0, v1;
    if constexpr (sizeof(T) == 4) {
        float2 pv = *(const float2*)&x[(size_t)row * 128 + c0];
        v0 = pv.x; v1 = pv.y;
    } else {
        unsigned int pv = *(const unsigned int*)&x[(size_t)row * 128 + c0];
        v0 = b2f((ushort_t)(pv & 0xffff));
        v1 = b2f((ushort_t)(pv >> 16));
    }
    float s  = v0 + v1;
    float s2 = v0 * v0 + v1 * v1;
    #pragma unroll
    for (int off = 32; off; off >>= 1) {
        s  += __shfl_xor(s,  off, 64);
        s2 += __shfl_xor(s2, off, 64);
    }
    float mu   = s * (1.0f / 128.0f);
    float var  = s2 * (1.0f / 128.0f) - mu * mu;
    float rstd = rsqrtf(var + 1e-5f);
    float o0 = (v0 - mu) * rstd * w[c0]     + b[c0];
    float o1 = (v1 - mu) * rstd * w[c0 + 1] + b[c0 + 1];
    unsigned int pk = (unsigned int)f2b(o0) | ((unsigned int)f2b(o1) << 16);
    *(unsigned int*)&out[(size_t)row * 128 + c0] = pk;
}

// ---------------- NT GEMM: out[M,N] = A[M,K] @ Bw[N,K]^T + bias -------------
// 128x128 tile, BK=64, 4 waves each 64x64 via 4x4 of 16x16x32 bf16 MFMA.
// Grid: x = n-block (fast -> A-tile L2 reuse), y = m-block.
// RESID: 0 none, 1 fp32 resid, 2 bf16 resid.  OUTF: fp32 output.
template<bool GELU, int RESID, bool OUTF>
__global__ __launch_bounds__(256, 2) void gemm_nt(
    const ushort_t* __restrict__ A, const ushort_t* __restrict__ Bw,
    const ushort_t* __restrict__ bias, const void* __restrict__ resid,
    void* __restrict__ out, int N, int Kdim)
{
    __shared__ ushort_t As[128][72];
    __shared__ ushort_t Bs[128][72];
    int n0 = blockIdx.x * 128, m0 = blockIdx.y * 128;
    int tid  = threadIdx.x;
    int wave = tid >> 6, lane = tid & 63;
    int wm = wave >> 1, wn = wave & 1;
    int quad = lane >> 4, lrow = lane & 15;

    f4 acc[4][4];
    #pragma unroll
    for (int i = 0; i < 4; i++)
        #pragma unroll
        for (int j = 0; j < 4; j++) {
            f4 z = {0.f, 0.f, 0.f, 0.f};
            acc[i][j] = z;
        }

    for (int k0 = 0; k0 < Kdim; k0 += 64) {
        #pragma unroll 4
        for (int i = tid; i < 1024; i += 256) {
            int r = i >> 3, c = (i & 7) << 3;
            *(uint4*)&As[r][c] = *(const uint4*)&A[(size_t)(m0 + r) * Kdim + k0 + c];
        }
        #pragma unroll 4
        for (int i = tid; i < 1024; i += 256) {
            int r = i >> 3, c = (i & 7) << 3;
            *(uint4*)&Bs[r][c] = *(const uint4*)&Bw[(size_t)(n0 + r) * Kdim + k0 + c];
        }
        __syncthreads();
        #pragma unroll
        for (int ks = 0; ks < 64; ks += 32) {
            bf8 av[4], bv[4];
            #pragma unroll
            for (int i = 0; i < 4; i++)
                av[i] = *(const bf8*)&As[wm * 64 + i * 16 + lrow][ks + quad * 8];
            #pragma unroll
            for (int j = 0; j < 4; j++)
                bv[j] = *(const bf8*)&Bs[wn * 64 + j * 16 + lrow][ks + quad * 8];
            #pragma unroll
            for (int i = 0; i < 4; i++)
                #pragma unroll
                for (int j = 0; j < 4; j++)
                    acc[i][j] = __builtin_amdgcn_mfma_f32_16x16x32_bf16(
                        av[i], bv[j], acc[i][j], 0, 0, 0);
        }
        __syncthreads();
    }

    float bs[4];
    #pragma unroll
    for (int j = 0; j < 4; j++) bs[j] = b2f(bias[n0 + wn * 64 + j * 16 + lrow]);

    #pragma unroll
    for (int i = 0; i < 4; i++) {
        #pragma unroll
        for (int r = 0; r < 4; r++) {
            int grow = m0 + wm * 64 + i * 16 + quad * 4 + r;
            #pragma unroll
            for (int j = 0; j < 4; j++) {
                int gcol = n0 + wn * 64 + j * 16 + lrow;
                float v = acc[i][j][r] + bs[j];
                if (GELU) v = 0.5f * v * (1.0f + erff(v * 0.70710678118654752f));
                if (RESID == 1) v += ((const float*)resid)[(size_t)grow * N + gcol];
                if (RESID == 2) v += b2f(((const ushort_t*)resid)[(size_t)grow * N + gcol]);
                if (OUTF) ((float*)out)[(size_t)grow * N + gcol] = v;
                else      ((ushort_t*)out)[(size_t)grow * N + gcol] = f2b(v);
            }
        }
    }
}

// ---------------- Neighborhood attention (k=7, 1-D over N=16384) ------------
// Block = 64 consecutive tokens (one image); thread = (token, head).
// K/V rows staged once into LDS; per-thread serial FMA dot products.
__global__ __launch_bounds__(256, 4) void nat_attn(
    const ushort_t* __restrict__ qkv, const float* __restrict__ rpb,
    ushort_t* __restrict__ out)
{
    __shared__ ushort_t kv[70][264];   // k: cols [0,128), v: cols [128,256); +8 pad
    int t0       = blockIdx.x * 64;           // chunk-local first token
    int img_base = t0 & ~(NPOS - 1);
    int n0       = t0 & (NPOS - 1);           // image-local
    int lo = n0 - 3;  if (lo < 0) lo = 0;
    int hi = n0 + 66; if (hi > NPOS - 1) hi = NPOS - 1;
    int cnt = hi - lo + 1;                    // <= 70
    int tid = threadIdx.x;

    // stage K,V: qkv rows [img_base+lo .. +hi], cols [128, 384) -> kv[r][0..256)
    for (int i = tid; i < cnt * 32; i += 256) {
        int r = i >> 5, c = (i & 31) << 3;
        *(uint4*)&kv[r][c] =
            *(const uint4*)&qkv[(size_t)(img_base + lo + r) * 384 + 128 + c];
    }

    // load own q while staging is in flight
    int lt = tid >> 2, head = tid & 3;
    int n  = n0 + lt;
    const ushort_t* qrow = qkv + (size_t)(img_base + n) * 384 + head * 32;
    float q[32];
    #pragma unroll
    for (int c8 = 0; c8 < 4; c8++) {
        uint4 pv = *(const uint4*)&qrow[c8 * 8];
        const ushort_t* us = (const ushort_t*)&pv;
        #pragma unroll
        for (int e = 0; e < 8; e++)
            q[c8 * 8 + e] = b2f(us[e]) * 0.17677669529663687f;
    }
    __syncthreads();

    int s = n - 3;
    if (s < 0) s = 0;
    if (s > NPOS - 7) s = NPOS - 7;
    int r0 = s - lo;

    float logit[7];
    #pragma unroll
    for (int j = 0; j < 7; j++) {
        const ushort_t* kr = &kv[r0 + j][head * 32];
        float a0 = 0.f, a1 = 0.f;
        #pragma unroll
        for (int c8 = 0; c8 < 4; c8++) {
            uint4 pv = *(const uint4*)&kr[c8 * 8];
            const ushort_t* us = (const ushort_t*)&pv;
            #pragma unroll
            for (int e = 0; e < 4; e++) {
                a0 += q[c8 * 8 + e]     * b2f(us[e]);
                a1 += q[c8 * 8 + e + 4] * b2f(us[e + 4]);
            }
        }
        logit[j] = a0 + a1 + rpb[head * 13 + (s + j - n + 6)];
    }

    float m = logit[0];
    #pragma unroll
    for (int j = 1; j < 7; j++) m = fmaxf(m, logit[j]);
    float e[7], esum = 0.f;
    #pragma unroll
    for (int j = 0; j < 7; j++) { e[j] = __expf(logit[j] - m); esum += e[j]; }
    float inv = 1.0f / esum;

    float o[32];
    #pragma unroll
    for (int c = 0; c < 32; c++) o[c] = 0.f;
    #pragma unroll
    for (int j = 0; j < 7; j++) {
        const ushort_t* vr = &kv[r0 + j][128 + head * 32];
        float ej = e[j];
        #pragma unroll
        for (int c8 = 0; c8 < 4; c8++) {
            uint4 pv = *(const uint4*)&vr[c8 * 8];
            const ushort_t* us = (const ushort_t*)&pv;
            #pragma unroll
            for (int e2 = 0; e2 < 8; e2++)
                o[c8 * 8 + e2] += ej * b2f(us[e2]);
        }
    }

    ushort_t* orow = out + (size_t)(t0 + lt) * 128 + head * 32;
    #pragma unroll
    for (int c8 = 0; c8 < 4; c8++) {
        unsigned int pk[4];
        #pragma unroll
        for (int p2 = 0; p2 < 4; p2++)
            pk[p2] = (unsigned int)f2b(o[c8 * 8 + p2 * 2] * inv)
                   | ((unsigned int)f2b(o[c8 * 8 + p2 * 2 + 1] * inv) << 16);
        *(uint4*)&orow[c8 * 8] = *(uint4*)pk;
    }
}

extern "C" void kernel_launch(void* const* d_in, const int* in_sizes, int n_in,
                              void* d_out, int out_size, void* d_ws, size_t ws_size,
                              hipStream_t stream) {
    const float* x      = (const float*)d_in[0];
    const float* n1w    = (const float*)d_in[1];
    const float* n1b    = (const float*)d_in[2];
    const float* qkv_w  = (const float*)d_in[3];
    const float* qkv_b  = (const float*)d_in[4];
    const float* rpb    = (const float*)d_in[5];
    const float* proj_w = (const float*)d_in[6];
    const float* proj_b = (const float*)d_in[7];
    const float* n2w    = (const float*)d_in[8];
    const float* n2b    = (const float*)d_in[9];
    const float* fc1_w  = (const float*)d_in[10];
    const float* fc1_b  = (const float*)d_in[11];
    const float* fc2_w  = (const float*)d_in[12];
    const float* fc2_b  = (const float*)d_in[13];

    ushort_t* ws      = (ushort_t*)d_ws;
    ushort_t* params  = ws;                     // 197,760 elems (pad to 262144)
    ushort_t* xs      = ws + 262144;            // 16,777,216 elems (also x2)
    ushort_t* x2      = xs;
    ushort_t* scratch = ws + 17039360;          // qkvchunk (25.2M) / hchunk (33.5M)
    // d_out (fp32, 67.1MB) doubles as bf16 scratch:
    ushort_t* attnout = (ushort_t*)d_out;               // bytes [0, 33.5MB)
    ushort_t* ys      = attnout + 16777216;             // bytes [33.5, 67.1MB)
    float*    outf    = (float*)d_out;

    const size_t RC = (size_t)CHUNK * 128;      // activation elems per chunk

    cvt_params<<<(P_TOTAL + 255) / 256, 256, 0, stream>>>(
        qkv_w, qkv_b, proj_w, proj_b, fc1_w, fc1_b, fc2_w, fc2_b, params);

    ln_kernel<float><<<MROWS / 4, 256, 0, stream>>>(x, n1w, n1b, xs);

    for (int c = 0; c < 2; c++) {
        gemm_nt<false, 0, false><<<dim3(3, CHUNK / 128), 256, 0, stream>>>(
            xs + c * RC, params + P_QKV_W, params + P_QKV_B, nullptr,
            scratch, 384, 128);
        nat_attn<<<CHUNK / 64, 256, 0, stream>>>(scratch, rpb, attnout + c * RC);
    }

    gemm_nt<false, 1, false><<<dim3(1, MROWS / 128), 256, 0, stream>>>(
        attnout, params + P_PROJ_W, params + P_PROJ_B, x, x2, 128, 128);

    ln_kernel<ushort_t><<<MROWS / 4, 256, 0, stream>>>(x2, n2w, n2b, ys);

    for (int c = 0; c < 2; c++) {
        gemm_nt<true, 0, false><<<dim3(4, CHUNK / 128), 256, 0, stream>>>(
            ys + c * RC, params + P_FC1_W, params + P_FC1_B, nullptr,
            scratch, 512, 128);
        gemm_nt<false, 2, true><<<dim3(1, CHUNK / 128), 256, 0, stream>>>(
            scratch, params + P_FC2_W, params + P_FC2_B, x2 + c * RC,
            outf + c * RC, 128, 512);
    }
}

// Round 4
// 346.249 us; speedup vs baseline: 1.4237x; 1.4237x over previous
//
#include <hip/hip_runtime.h>
#include <hip/hip_bf16.h>

// NATLayer fp32 I/O, bf16 internal compute. B=8, H=W=128, C=128, HEADS=4,
// d=32, KSIZE=7, N=16384 (1-D neighborhood over flattened N), M = B*N = 131072.
//
// Round 4: fused 4-dispatch pipeline.
//  0. cvt_params: fp32 weights -> bf16 param block            [ws]
//  1. K1: LN1 + QKV(MFMA) + neighborhood attention -> attnout [ws]
//  2. K2: proj(MFMA) + x residual + LN2 -> x2(bf16) + ys      [ws]
//  3. K3: fc1(MFMA) + gelu + fc2(MFMA) + x2 resid -> out fp32 [d_out]
// Intermediates qkv and h never touch HBM (LDS only).

#define NPOS 16384
#define MROWS 131072

typedef unsigned short ushort_t;
typedef __bf16 bf8 __attribute__((ext_vector_type(8)));
typedef float f4 __attribute__((ext_vector_type(4)));

// param block offsets (bf16 elems)
#define P_QKV_W 0
#define P_QKV_B 49152
#define P_PROJ_W 49536
#define P_PROJ_B 65920
#define P_FC1_W 66048
#define P_FC1_B 131584
#define P_FC2_W 132096
#define P_FC2_B 197632
#define P_TOTAL 197760

__device__ __forceinline__ float b2f(ushort_t u) {
    union { unsigned int i; float f; } v; v.i = ((unsigned int)u) << 16; return v.f;
}
__device__ __forceinline__ ushort_t f2b(float f) {
    __hip_bfloat16 h = __float2bfloat16(f);
    return *reinterpret_cast<ushort_t*>(&h);
}
__device__ __forceinline__ void ld8(const ushort_t* p, float* d) {
    uint4 pv = *(const uint4*)p;
    const ushort_t* us = (const ushort_t*)&pv;
    #pragma unroll
    for (int e = 0; e < 8; e++) d[e] = b2f(us[e]);
}
__device__ __forceinline__ void st8(ushort_t* p, const float* d) {
    unsigned int pk[4];
    #pragma unroll
    for (int e = 0; e < 4; e++)
        pk[e] = (unsigned int)f2b(d[2 * e]) | ((unsigned int)f2b(d[2 * e + 1]) << 16);
    *(uint4*)p = *(uint4*)pk;
}

// ---------------- fp32 -> bf16 weight conversion (one launch) ---------------
__global__ __launch_bounds__(256) void cvt_params(
    const float* __restrict__ qkv_w, const float* __restrict__ qkv_b,
    const float* __restrict__ proj_w, const float* __restrict__ proj_b,
    const float* __restrict__ fc1_w, const float* __restrict__ fc1_b,
    const float* __restrict__ fc2_w, const float* __restrict__ fc2_b,
    ushort_t* __restrict__ p)
{
    int i = blockIdx.x * 256 + threadIdx.x;
    if (i >= P_TOTAL) return;
    float v;
    if      (i < P_QKV_B)  v = qkv_w[i - P_QKV_W];
    else if (i < P_PROJ_W) v = qkv_b[i - P_QKV_B];
    else if (i < P_PROJ_B) v = proj_w[i - P_PROJ_W];
    else if (i < P_FC1_W)  v = proj_b[i - P_PROJ_B];
    else if (i < P_FC1_B)  v = fc1_w[i - P_FC1_W];
    else if (i < P_FC2_W)  v = fc1_b[i - P_FC1_B];
    else if (i < P_FC2_B)  v = fc2_w[i - P_FC2_W];
    else                   v = fc2_b[i - P_FC2_B];
    p[i] = f2b(v);
}

// ================= K1: LN1 + QKV + neighborhood attention ===================
// Block = 128 tokens (+8 halo rows each side => 144 rows), 512 threads.
// Dyn LDS: xs[144][128] swizzled (36864 B) | kv[144][264] (76032 B)
//          | qo[128][136] (34816 B)  -> total 147712 B.
__global__ __launch_bounds__(512, 2) void k1_ln_qkv_attn(
    const float* __restrict__ x, const float* __restrict__ n1w,
    const float* __restrict__ n1b, const ushort_t* __restrict__ qkvw,
    const float* __restrict__ qkvb, const float* __restrict__ rpb,
    ushort_t* __restrict__ attnout)
{
    extern __shared__ ushort_t sm[];
    ushort_t* xs = sm;            // shorts [0, 18432): row stride 128, swizzled
    ushort_t* kv = sm + 18432;    // shorts [18432, 56448): row stride 264
    ushort_t* qo = sm + 56448;    // shorts [56448, 73856): row stride 136

    int t0 = blockIdx.x * 128;
    int img_base = t0 & ~(NPOS - 1);
    int nl0 = t0 & (NPOS - 1);
    int tid = threadIdx.x;
    int w = tid >> 6, lane = tid & 63;

    // ---- phase 1: LN1 of rows [t0-8, t0+136), one wave per row ----
    {
        int c0 = lane * 2;
        float wg0 = n1w[c0], wg1 = n1w[c0 + 1];
        float bb0 = n1b[c0], bb1 = n1b[c0 + 1];
        int nl = nl0 - 8 + w;
        nl = min(max(nl, 0), NPOS - 1);
        float2 cur = *(const float2*)&x[(size_t)(img_base + nl) * 128 + c0];
        for (int it = 0; it < 18; it++) {
            float2 nxt = cur;
            if (it < 17) {
                int nl2 = nl0 - 8 + (it + 1) * 8 + w;
                nl2 = min(max(nl2, 0), NPOS - 1);
                nxt = *(const float2*)&x[(size_t)(img_base + nl2) * 128 + c0];
            }
            int r = it * 8 + w;
            float v0 = cur.x, v1 = cur.y;
            float s = v0 + v1, s2 = v0 * v0 + v1 * v1;
            #pragma unroll
            for (int off = 32; off; off >>= 1) {
                s  += __shfl_xor(s,  off, 64);
                s2 += __shfl_xor(s2, off, 64);
            }
            float mu   = s * (1.0f / 128.0f);
            float rstd = rsqrtf(s2 * (1.0f / 128.0f) - mu * mu + 1e-5f);
            float o0 = (v0 - mu) * rstd * wg0 + bb0;
            float o1 = (v1 - mu) * rstd * wg1 + bb1;
            unsigned int pk = (unsigned int)f2b(o0) | ((unsigned int)f2b(o1) << 16);
            int off16 = r * 128 + ((((c0 >> 3) ^ (r & 7)) << 3) | (c0 & 7));
            *(unsigned int*)&xs[off16] = pk;
            cur = nxt;
        }
    }
    __syncthreads();

    // ---- phase 2: QKV GEMM. M=144 (9 tiles), N=384; wave w: N-tiles 3w..3w+2
    {
        int quad = lane >> 4, lrow = lane & 15;
        f4 acc[9][3];
        #pragma unroll
        for (int i = 0; i < 9; i++)
            #pragma unroll
            for (int j = 0; j < 3; j++) {
                f4 z = {0.f, 0.f, 0.f, 0.f};
                acc[i][j] = z;
            }
        float bias_j[3];
        #pragma unroll
        for (int jj = 0; jj < 3; jj++)
            bias_j[jj] = qkvb[(3 * w + jj) * 16 + lrow];

        for (int k0 = 0; k0 < 128; k0 += 32) {
            bf8 bv[3];
            #pragma unroll
            for (int jj = 0; jj < 3; jj++) {
                int n = (3 * w + jj) * 16 + lrow;
                bv[jj] = *(const bf8*)&qkvw[(size_t)n * 128 + k0 + quad * 8];
            }
            #pragma unroll
            for (int i = 0; i < 9; i++) {
                int row = i * 16 + lrow;
                int kq = (k0 >> 3) + quad;
                bf8 av = *(const bf8*)&xs[row * 128 + ((kq ^ (row & 7)) << 3)];
                #pragma unroll
                for (int jj = 0; jj < 3; jj++)
                    acc[i][jj] = __builtin_amdgcn_mfma_f32_16x16x32_bf16(
                        av, bv[jj], acc[i][jj], 0, 0, 0);
            }
        }
        #pragma unroll
        for (int jj = 0; jj < 3; jj++) {
            int jt = 3 * w + jj;
            int n = jt * 16 + lrow;
            bool isQ = (jt < 8);
            #pragma unroll
            for (int i = 0; i < 9; i++) {
                #pragma unroll
                for (int r = 0; r < 4; r++) {
                    int mrow = i * 16 + quad * 4 + r;
                    float v = acc[i][jj][r] + bias_j[jj];
                    if (isQ) {
                        if (mrow >= 8 && mrow < 136)
                            qo[(mrow - 8) * 136 + n] = f2b(v * 0.17677669529663687f);
                    } else {
                        kv[mrow * 264 + (n - 128)] = f2b(v);
                    }
                }
            }
        }
    }
    __syncthreads();

    // ---- phase 3: attention. thread = (head = tid>>7, token = tid&127) ----
    {
        int t = tid & 127, head = tid >> 7;
        int n = nl0 + t;
        int s = n - 3;
        if (s < 0) s = 0;
        if (s > NPOS - 7) s = NPOS - 7;
        int r0 = s - nl0 + 8;          // kv/xs row of first neighbor

        float q[32];
        #pragma unroll
        for (int c8 = 0; c8 < 4; c8++)
            ld8(&qo[t * 136 + head * 32 + c8 * 8], &q[c8 * 8]);

        float logit[7];
        #pragma unroll
        for (int j = 0; j < 7; j++) {
            const ushort_t* kr = &kv[(r0 + j) * 264 + head * 32];
            float kk[8];
            float a0 = 0.f, a1 = 0.f;
            #pragma unroll
            for (int c8 = 0; c8 < 4; c8++) {
                ld8(&kr[c8 * 8], kk);
                #pragma unroll
                for (int e = 0; e < 4; e++) {
                    a0 += q[c8 * 8 + e]     * kk[e];
                    a1 += q[c8 * 8 + e + 4] * kk[e + 4];
                }
            }
            logit[j] = a0 + a1 + rpb[head * 13 + (s + j - n + 6)];
        }
        float m = logit[0];
        #pragma unroll
        for (int j = 1; j < 7; j++) m = fmaxf(m, logit[j]);
        float e[7], esum = 0.f;
        #pragma unroll
        for (int j = 0; j < 7; j++) { e[j] = __expf(logit[j] - m); esum += e[j]; }
        float inv = 1.0f / esum;

        float o[32];
        #pragma unroll
        for (int c = 0; c < 32; c++) o[c] = 0.f;
        #pragma unroll
        for (int j = 0; j < 7; j++) {
            const ushort_t* vr = &kv[(r0 + j) * 264 + 128 + head * 32];
            float vvv[8];
            float ej = e[j];
            #pragma unroll
            for (int c8 = 0; c8 < 4; c8++) {
                ld8(&vr[c8 * 8], vvv);
                #pragma unroll
                for (int e2 = 0; e2 < 8; e2++)
                    o[c8 * 8 + e2] += ej * vvv[e2];
            }
        }
        #pragma unroll
        for (int c = 0; c < 32; c++) o[c] *= inv;
        #pragma unroll
        for (int c8 = 0; c8 < 4; c8++)
            st8(&qo[t * 136 + head * 32 + c8 * 8], &o[c8 * 8]);
    }
    __syncthreads();

    // ---- phase 4: coalesced store of attnout (128 rows x 128 cols) ----
    #pragma unroll
    for (int it = 0; it < 4; it++) {
        int qd = it * 512 + tid;
        int r = qd >> 4, lq = qd & 15;
        uint4 v = *(const uint4*)&qo[r * 136 + lq * 8];
        *(uint4*)&attnout[(size_t)(t0 + r) * 128 + lq * 8] = v;
    }
}

// ================= K2: proj + x residual + LN2 ==============================
// Block = 128 rows, 256 threads. Static LDS 36864 B (As/Bs, reused as c_tile).
__global__ __launch_bounds__(256, 2) void k2_proj_ln(
    const ushort_t* __restrict__ A, const ushort_t* __restrict__ Bw,
    const float* __restrict__ bias, const float* __restrict__ xresid,
    const float* __restrict__ n2w, const float* __restrict__ n2b,
    ushort_t* __restrict__ x2out, ushort_t* __restrict__ ysout)
{
    __shared__ ushort_t smem[18432];
    ushort_t* As = smem;            // [128][72]
    ushort_t* Bs = smem + 9216;     // [128][72]
    ushort_t* ct = smem;            // [128][132] overlay (16896 shorts)

    int m0 = blockIdx.x * 128;
    int tid = threadIdx.x;
    int wave = tid >> 6, lane = tid & 63;
    int wm = wave >> 1, wn = wave & 1;
    int quad = lane >> 4, lrow = lane & 15;

    f4 acc[4][4];
    #pragma unroll
    for (int i = 0; i < 4; i++)
        #pragma unroll
        for (int j = 0; j < 4; j++) {
            f4 z = {0.f, 0.f, 0.f, 0.f};
            acc[i][j] = z;
        }

    for (int k0 = 0; k0 < 128; k0 += 64) {
        #pragma unroll 4
        for (int i = tid; i < 1024; i += 256) {
            int r = i >> 3, c = (i & 7) << 3;
            *(uint4*)&As[r * 72 + c] = *(const uint4*)&A[(size_t)(m0 + r) * 128 + k0 + c];
        }
        #pragma unroll 4
        for (int i = tid; i < 1024; i += 256) {
            int r = i >> 3, c = (i & 7) << 3;
            *(uint4*)&Bs[r * 72 + c] = *(const uint4*)&Bw[(size_t)r * 128 + k0 + c];
        }
        __syncthreads();
        #pragma unroll
        for (int ks = 0; ks < 64; ks += 32) {
            bf8 av[4], bv[4];
            #pragma unroll
            for (int i = 0; i < 4; i++)
                av[i] = *(const bf8*)&As[(wm * 64 + i * 16 + lrow) * 72 + ks + quad * 8];
            #pragma unroll
            for (int j = 0; j < 4; j++)
                bv[j] = *(const bf8*)&Bs[(wn * 64 + j * 16 + lrow) * 72 + ks + quad * 8];
            #pragma unroll
            for (int i = 0; i < 4; i++)
                #pragma unroll
                for (int j = 0; j < 4; j++)
                    acc[i][j] = __builtin_amdgcn_mfma_f32_16x16x32_bf16(
                        av[i], bv[j], acc[i][j], 0, 0, 0);
        }
        __syncthreads();
    }

    // epilogue: + bias + fp32 x residual -> c_tile (bf16 = x2 values)
    float bs[4];
    #pragma unroll
    for (int j = 0; j < 4; j++) bs[j] = bias[wn * 64 + j * 16 + lrow];
    #pragma unroll
    for (int i = 0; i < 4; i++) {
        #pragma unroll
        for (int r = 0; r < 4; r++) {
            int rl = wm * 64 + i * 16 + quad * 4 + r;
            #pragma unroll
            for (int j = 0; j < 4; j++) {
                int cl = wn * 64 + j * 16 + lrow;
                float v = acc[i][j][r] + bs[j]
                        + xresid[(size_t)(m0 + rl) * 128 + cl];
                ct[rl * 132 + cl] = f2b(v);
            }
        }
    }
    __syncthreads();

    // LN2 tail: one wave per row
    int c0 = lane * 2;
    float wg0 = n2w[c0], wg1 = n2w[c0 + 1];
    float bb0 = n2b[c0], bb1 = n2b[c0 + 1];
    for (int it = 0; it < 32; it++) {
        int r = it * 4 + wave;
        unsigned int pv = *(const unsigned int*)&ct[r * 132 + c0];
        float v0 = b2f((ushort_t)(pv & 0xffff));
        float v1 = b2f((ushort_t)(pv >> 16));
        float s = v0 + v1, s2 = v0 * v0 + v1 * v1;
        #pragma unroll
        for (int off = 32; off; off >>= 1) {
            s  += __shfl_xor(s,  off, 64);
            s2 += __shfl_xor(s2, off, 64);
        }
        float mu   = s * (1.0f / 128.0f);
        float rstd = rsqrtf(s2 * (1.0f / 128.0f) - mu * mu + 1e-5f);
        float o0 = (v0 - mu) * rstd * wg0 + bb0;
        float o1 = (v1 - mu) * rstd * wg1 + bb1;
        *(unsigned int*)&x2out[(size_t)(m0 + r) * 128 + c0] = pv;
        unsigned int pk = (unsigned int)f2b(o0) | ((unsigned int)f2b(o1) << 16);
        *(unsigned int*)&ysout[(size_t)(m0 + r) * 128 + c0] = pk;
    }
}

// ================= K3: fc1 + gelu + fc2 + residual ==========================
// Block = 64 rows, 512 threads. Dyn LDS: ysT[64][136] (17408 B) +
// h[64][512] swizzled (65536 B) = 82944 B.
__global__ __launch_bounds__(512, 2) void k3_mlp(
    const ushort_t* __restrict__ ys, const ushort_t* __restrict__ fc1w,
    const float* __restrict__ fc1b, const ushort_t* __restrict__ fc2w,
    const float* __restrict__ fc2b, const ushort_t* __restrict__ x2,
    float* __restrict__ out)
{
    extern __shared__ ushort_t sm[];
    ushort_t* ysT = sm;           // [64][136] padded
    ushort_t* h   = sm + 8704;    // [64][512] swizzled

    int row0 = blockIdx.x * 64;
    int tid = threadIdx.x;
    int w = tid >> 6, lane = tid & 63;
    int quad = lane >> 4, lrow = lane & 15;

    // stage ys tile (64 x 128)
    #pragma unroll
    for (int it = 0; it < 2; it++) {
        int qd = it * 512 + tid;
        int r = qd >> 4, lq = qd & 15;
        *(uint4*)&ysT[r * 136 + lq * 8] =
            *(const uint4*)&ys[(size_t)(row0 + r) * 128 + lq * 8];
    }
    __syncthreads();

    // ---- fc1: M=64, N=512; wave w owns cols [64w, 64w+64) ----
    {
        f4 acc[4][4];
        #pragma unroll
        for (int i = 0; i < 4; i++)
            #pragma unroll
            for (int j = 0; j < 4; j++) {
                f4 z = {0.f, 0.f, 0.f, 0.f};
                acc[i][j] = z;
            }
        for (int k0 = 0; k0 < 128; k0 += 32) {
            bf8 bv[4];
            #pragma unroll
            for (int j = 0; j < 4; j++) {
                int n = w * 64 + j * 16 + lrow;
                bv[j] = *(const bf8*)&fc1w[(size_t)n * 128 + k0 + quad * 8];
            }
            #pragma unroll
            for (int i = 0; i < 4; i++) {
                bf8 av = *(const bf8*)&ysT[(i * 16 + lrow) * 136 + k0 + quad * 8];
                #pragma unroll
                for (int j = 0; j < 4; j++)
                    acc[i][j] = __builtin_amdgcn_mfma_f32_16x16x32_bf16(
                        av, bv[j], acc[i][j], 0, 0, 0);
            }
        }
        float bs[4];
        #pragma unroll
        for (int j = 0; j < 4; j++) bs[j] = fc1b[w * 64 + j * 16 + lrow];
        #pragma unroll
        for (int i = 0; i < 4; i++) {
            #pragma unroll
            for (int r = 0; r < 4; r++) {
                int row = i * 16 + quad * 4 + r;
                #pragma unroll
                for (int j = 0; j < 4; j++) {
                    int col = w * 64 + j * 16 + lrow;
                    float v = acc[i][j][r] + bs[j];
                    v = 0.5f * v * (1.0f + erff(v * 0.70710678118654752f));
                    h[row * 512 + ((((col >> 3) ^ (row & 7)) << 3) | (col & 7))] = f2b(v);
                }
            }
        }
    }
    __syncthreads();

    // ---- fc2: M=64, N=128; wave w owns N-tile w (cols 16w..16w+16) ----
    {
        f4 acc2[4];
        #pragma unroll
        for (int i = 0; i < 4; i++) {
            f4 z = {0.f, 0.f, 0.f, 0.f};
            acc2[i] = z;
        }
        int n = w * 16 + lrow;
        for (int k0 = 0; k0 < 512; k0 += 32) {
            bf8 bv = *(const bf8*)&fc2w[(size_t)n * 512 + k0 + quad * 8];
            #pragma unroll
            for (int i = 0; i < 4; i++) {
                int row = i * 16 + lrow;
                int kq = (k0 >> 3) + quad;
                bf8 av = *(const bf8*)&h[row * 512 + ((kq ^ (row & 7)) << 3)];
                acc2[i] = __builtin_amdgcn_mfma_f32_16x16x32_bf16(
                    av, bv, acc2[i], 0, 0, 0);
            }
        }
        float bs2 = fc2b[n];
        #pragma unroll
        for (int i = 0; i < 4; i++) {
            #pragma unroll
            for (int r = 0; r < 4; r++) {
                int grow = row0 + i * 16 + quad * 4 + r;
                float v = acc2[i][r] + bs2 + b2f(x2[(size_t)grow * 128 + n]);
                out[(size_t)grow * 128 + n] = v;
            }
        }
    }
}

extern "C" void kernel_launch(void* const* d_in, const int* in_sizes, int n_in,
                              void* d_out, int out_size, void* d_ws, size_t ws_size,
                              hipStream_t stream) {
    const float* x      = (const float*)d_in[0];
    const float* n1w    = (const float*)d_in[1];
    const float* n1b    = (const float*)d_in[2];
    const float* qkv_w  = (const float*)d_in[3];
    const float* qkv_b  = (const float*)d_in[4];
    const float* rpb    = (const float*)d_in[5];
    const float* proj_w = (const float*)d_in[6];
    const float* proj_b = (const float*)d_in[7];
    const float* n2w    = (const float*)d_in[8];
    const float* n2b    = (const float*)d_in[9];
    const float* fc1_w  = (const float*)d_in[10];
    const float* fc1_b  = (const float*)d_in[11];
    const float* fc2_w  = (const float*)d_in[12];
    const float* fc2_b  = (const float*)d_in[13];

    ushort_t* ws      = (ushort_t*)d_ws;
    ushort_t* params  = ws;                       // [0, 262144)
    ushort_t* attnout = ws + 262144;              // 16.7M elems
    ushort_t* x2      = ws + 17039360;            // 16.7M elems
    ushort_t* ys      = ws + 33816576;            // 16.7M elems (end 50.6M = 101MB)
    float*    outf    = (float*)d_out;

    cvt_params<<<(P_TOTAL + 255) / 256, 256, 0, stream>>>(
        qkv_w, qkv_b, proj_w, proj_b, fc1_w, fc1_b, fc2_w, fc2_b, params);

    k1_ln_qkv_attn<<<MROWS / 128, 512, 147712, stream>>>(
        x, n1w, n1b, params + P_QKV_W, qkv_b, rpb, attnout);

    k2_proj_ln<<<MROWS / 128, 256, 0, stream>>>(
        attnout, params + P_PROJ_W, proj_b, x, n2w, n2b, x2, ys);

    k3_mlp<<<MROWS / 64, 512, 82944, stream>>>(
        ys, params + P_FC1_W, fc1_b, params + P_FC2_W, fc2_b, x2, outf);
}

// Round 5
// 345.460 us; speedup vs baseline: 1.4269x; 1.0023x over previous
//
#include <hip/hip_runtime.h>
#include <hip/hip_bf16.h>

// NATLayer fp32 I/O, bf16 internal. B=8, H=W=128, C=128, HEADS=4, d=32, K=7,
// N=16384 (1-D neighborhood over flattened N), M = B*N = 131072.
//
// Round 5: 3 dispatches.
//  0. cvt_params: fp32 weights -> bf16 param block
//  1. K1 (64 tokens/block, 80.1 KB LDS, 2 blocks/CU):
//     LN1 + QKV(MFMA) + attention + proj(MFMA) + x-resid + LN2 -> x2, ys
//  2. K3 (64 rows/block, 51.2 KB LDS, 2 blocks/CU):
//     fc1(MFMA) + gelu + fc2(MFMA, h in LDS by 256-wide K-halves) + x2 resid -> out
// All C-layout LDS tiles use blk-XOR swizzle (key=(row>>2)&3) + pad-8 rows:
// conflict-free for both scalar C-layout writes and bf8 A-frag reads.

#define NPOS 16384
#define MROWS 131072

typedef unsigned short ushort_t;
typedef __bf16 bf8 __attribute__((ext_vector_type(8)));
typedef float f4 __attribute__((ext_vector_type(4)));

#define P_QKV_W 0
#define P_QKV_B 49152
#define P_PROJ_W 49536
#define P_PROJ_B 65920
#define P_FC1_W 66048
#define P_FC1_B 131584
#define P_FC2_W 132096
#define P_FC2_B 197632
#define P_TOTAL 197760

__device__ __forceinline__ float b2f(ushort_t u) {
    union { unsigned int i; float f; } v; v.i = ((unsigned int)u) << 16; return v.f;
}
__device__ __forceinline__ ushort_t f2b(float f) {
    __hip_bfloat16 h = __float2bfloat16(f);
    return *reinterpret_cast<ushort_t*>(&h);
}
// blk-XOR swizzled LDS address (shorts); key=(row>>2)&3, 8-short blocks.
__device__ __forceinline__ int swz(int row, int col, int stride) {
    return row * stride + ((((col >> 3) ^ ((row >> 2) & 3)) << 3) | (col & 7));
}
// stride-128 tile needs stronger key (row&7) since 128 shorts == 0 mod 32 banks
__device__ __forceinline__ int swz8(int row, int col) {
    return row * 128 + ((((col >> 3) ^ (row & 7)) << 3) | (col & 7));
}
__device__ __forceinline__ void ld8(const ushort_t* p, float* d) {
    uint4 pv = *(const uint4*)p;
    const ushort_t* us = (const ushort_t*)&pv;
    #pragma unroll
    for (int e = 0; e < 8; e++) d[e] = b2f(us[e]);
}
__device__ __forceinline__ void st8(ushort_t* p, const float* d) {
    unsigned int pk[4];
    #pragma unroll
    for (int e = 0; e < 4; e++)
        pk[e] = (unsigned int)f2b(d[2 * e]) | ((unsigned int)f2b(d[2 * e + 1]) << 16);
    *(uint4*)p = *(uint4*)pk;
}
__device__ __forceinline__ float fast_gelu(float x) {
    // tanh-form GELU, ~1e-3 abs err (below bf16 h quantization)
    float u = x * (0.7978845608f + 0.0356774081f * x * x);
    float t = 1.0f - 2.0f / (1.0f + __expf(2.0f * u));
    return 0.5f * x * (1.0f + t);
}

__global__ __launch_bounds__(256) void cvt_params(
    const float* __restrict__ qkv_w, const float* __restrict__ qkv_b,
    const float* __restrict__ proj_w, const float* __restrict__ proj_b,
    const float* __restrict__ fc1_w, const float* __restrict__ fc1_b,
    const float* __restrict__ fc2_w, const float* __restrict__ fc2_b,
    ushort_t* __restrict__ p)
{
    int i = blockIdx.x * 256 + threadIdx.x;
    if (i >= P_TOTAL) return;
    float v;
    if      (i < P_QKV_B)  v = qkv_w[i - P_QKV_W];
    else if (i < P_PROJ_W) v = qkv_b[i - P_QKV_B];
    else if (i < P_PROJ_B) v = proj_w[i - P_PROJ_W];
    else if (i < P_FC1_W)  v = proj_b[i - P_PROJ_B];
    else if (i < P_FC1_B)  v = fc1_w[i - P_FC1_W];
    else if (i < P_FC2_W)  v = fc1_b[i - P_FC1_B];
    else if (i < P_FC2_B)  v = fc2_w[i - P_FC2_W];
    else                   v = fc2_b[i - P_FC2_B];
    p[i] = f2b(v);
}

// ======== K1: LN1 + QKV + attention + proj + residual + LN2 =================
// 64 tokens/block (+8 halo each side -> 80 rows), 512 threads.
// LDS shorts: xs[80][128] swz8 (10240) | kv[80][264] swz (21120)
//             | xres[64][136] swz (8704); qo overlays xs, ct overlays kv.
// Total 40064 shorts = 80128 B -> 2 blocks/CU.
__global__ __launch_bounds__(512, 2) void k1_fused(
    const float* __restrict__ x, const float* __restrict__ n1w,
    const float* __restrict__ n1b, const ushort_t* __restrict__ qkvw,
    const float* __restrict__ qkvb, const float* __restrict__ rpb,
    const ushort_t* __restrict__ projw, const float* __restrict__ projb,
    const float* __restrict__ n2w, const float* __restrict__ n2b,
    ushort_t* __restrict__ x2out, ushort_t* __restrict__ ysout)
{
    extern __shared__ ushort_t sm[];
    ushort_t* xs   = sm;           // [80][128] swizzled (swz8)
    ushort_t* kv   = sm + 10240;   // [80][264] (swz)
    ushort_t* xres = sm + 31360;   // [64][136] (swz)
    ushort_t* qo   = sm;           // overlay: [64][136] (swz)
    ushort_t* ct   = sm + 10240;   // overlay: [64][136] (swz)

    int t0  = blockIdx.x * 64;
    int ib  = t0 & ~(NPOS - 1);
    int nl0 = t0 & (NPOS - 1);
    int tid = threadIdx.x;
    int w = tid >> 6, lane = tid & 63;
    int quad = lane >> 4, lrow = lane & 15;

    // ---- phase 1: LN1 of 80 rows; also park raw x (bf16) for the residual
    {
        int c0 = lane * 2;
        float w0 = n1w[c0], w1 = n1w[c0 + 1];
        float b0 = n1b[c0], b1 = n1b[c0 + 1];
        #pragma unroll
        for (int it = 0; it < 10; it++) {
            int r = it * 8 + w;
            int nl = min(max(nl0 - 8 + r, 0), NPOS - 1);
            float2 v = *(const float2*)&x[(size_t)(ib + nl) * 128 + c0];
            float s = v.x + v.y, s2 = v.x * v.x + v.y * v.y;
            #pragma unroll
            for (int off = 32; off; off >>= 1) {
                s  += __shfl_xor(s,  off, 64);
                s2 += __shfl_xor(s2, off, 64);
            }
            float mu   = s * (1.0f / 128.0f);
            float rstd = rsqrtf(s2 * (1.0f / 128.0f) - mu * mu + 1e-5f);
            float o0 = (v.x - mu) * rstd * w0 + b0;
            float o1 = (v.y - mu) * rstd * w1 + b1;
            unsigned int pk = (unsigned int)f2b(o0) | ((unsigned int)f2b(o1) << 16);
            *(unsigned int*)&xs[swz8(r, c0)] = pk;
            if (r >= 8 && r < 72) {
                unsigned int pr = (unsigned int)f2b(v.x) | ((unsigned int)f2b(v.y) << 16);
                *(unsigned int*)&xres[swz(r - 8, c0, 136)] = pr;
            }
        }
    }
    __syncthreads();

    // ---- phase 2: QKV GEMM. M=80 (5 tiles), N=384 (24 tiles, 3/wave)
    {
        f4 acc[5][3];
        #pragma unroll
        for (int i = 0; i < 5; i++)
            #pragma unroll
            for (int j = 0; j < 3; j++) { f4 z = {0.f,0.f,0.f,0.f}; acc[i][j] = z; }
        #pragma unroll
        for (int k0 = 0; k0 < 128; k0 += 32) {
            bf8 bv[3];
            #pragma unroll
            for (int jj = 0; jj < 3; jj++) {
                int n = (3 * w + jj) * 16 + lrow;
                bv[jj] = *(const bf8*)&qkvw[(size_t)n * 128 + k0 + quad * 8];
            }
            #pragma unroll
            for (int i = 0; i < 5; i++) {
                bf8 av = *(const bf8*)&xs[swz8(i * 16 + lrow, k0 + quad * 8)];
                #pragma unroll
                for (int jj = 0; jj < 3; jj++)
                    acc[i][jj] = __builtin_amdgcn_mfma_f32_16x16x32_bf16(
                        av, bv[jj], acc[i][jj], 0, 0, 0);
            }
        }
        __syncthreads();          // xs reads done before qo overlay writes
        #pragma unroll
        for (int jj = 0; jj < 3; jj++) {
            int jt = 3 * w + jj;
            int n = jt * 16 + lrow;
            float bj = qkvb[n];
            #pragma unroll
            for (int i = 0; i < 5; i++) {
                #pragma unroll
                for (int r = 0; r < 4; r++) {
                    int mrow = i * 16 + quad * 4 + r;
                    float v = acc[i][jj][r] + bj;
                    if (jt < 8) {
                        if (mrow >= 8 && mrow < 72)
                            qo[swz(mrow - 8, n, 136)] = f2b(v * 0.17677669529663687f);
                    } else {
                        kv[swz(mrow, n - 128, 264)] = f2b(v);
                    }
                }
            }
        }
    }
    __syncthreads();

    // ---- phase 3: attention. thread = (token=tid>>3, head=(tid>>1)&3, half=tid&1)
    {
        int t = tid >> 3, head = (tid >> 1) & 3, half = tid & 1;
        int n = nl0 + t;
        int s = n - 3;
        if (s < 0) s = 0;
        if (s > NPOS - 7) s = NPOS - 7;
        int r0 = s - nl0 + 8;
        int cb = head * 32 + half * 16;

        float q[16];
        ld8(&qo[swz(t, cb, 136)], q);
        ld8(&qo[swz(t, cb + 8, 136)], q + 8);

        float logit[7];
        #pragma unroll
        for (int j = 0; j < 7; j++) {
            int row = r0 + j;
            float kk[8];
            float p = 0.f;
            ld8(&kv[swz(row, cb, 264)], kk);
            #pragma unroll
            for (int e = 0; e < 8; e++) p += q[e] * kk[e];
            ld8(&kv[swz(row, cb + 8, 264)], kk);
            #pragma unroll
            for (int e = 0; e < 8; e++) p += q[8 + e] * kk[e];
            p += __shfl_xor(p, 1, 64);   // combine the two 16-chan halves
            logit[j] = p + rpb[head * 13 + (s + j - n + 6)];
        }
        float m = logit[0];
        #pragma unroll
        for (int j = 1; j < 7; j++) m = fmaxf(m, logit[j]);
        float e[7], esum = 0.f;
        #pragma unroll
        for (int j = 0; j < 7; j++) { e[j] = __expf(logit[j] - m); esum += e[j]; }
        float inv = 1.0f / esum;

        float o[16];
        #pragma unroll
        for (int c = 0; c < 16; c++) o[c] = 0.f;
        #pragma unroll
        for (int j = 0; j < 7; j++) {
            int row = r0 + j;
            float vv[8];
            float ej = e[j];
            ld8(&kv[swz(row, 128 + cb, 264)], vv);
            #pragma unroll
            for (int c = 0; c < 8; c++) o[c] += ej * vv[c];
            ld8(&kv[swz(row, 128 + cb + 8, 264)], vv);
            #pragma unroll
            for (int c = 0; c < 8; c++) o[8 + c] += ej * vv[c];
        }
        #pragma unroll
        for (int c = 0; c < 16; c++) o[c] *= inv;
        st8(&qo[swz(t, cb, 136)], o);
        st8(&qo[swz(t, cb + 8, 136)], o + 8);
    }
    __syncthreads();

    // ---- phase 4: proj (M=64, N=128; wave w owns N-tile w) + resid -> ct
    {
        int n = w * 16 + lrow;
        f4 acc2[4];
        #pragma unroll
        for (int i = 0; i < 4; i++) { f4 z = {0.f,0.f,0.f,0.f}; acc2[i] = z; }
        #pragma unroll
        for (int k0 = 0; k0 < 128; k0 += 32) {
            bf8 bv = *(const bf8*)&projw[(size_t)n * 128 + k0 + quad * 8];
            #pragma unroll
            for (int i = 0; i < 4; i++) {
                bf8 av = *(const bf8*)&qo[swz(i * 16 + lrow, k0 + quad * 8, 136)];
                acc2[i] = __builtin_amdgcn_mfma_f32_16x16x32_bf16(av, bv, acc2[i], 0, 0, 0);
            }
        }
        float bj = projb[n];
        #pragma unroll
        for (int i = 0; i < 4; i++) {
            #pragma unroll
            for (int r = 0; r < 4; r++) {
                int row = i * 16 + quad * 4 + r;
                float v = acc2[i][r] + bj + b2f(xres[swz(row, n, 136)]);
                ct[swz(row, n, 136)] = f2b(v);
            }
        }
    }
    __syncthreads();

    // ---- phase 5: LN2 + global stores of x2, ys
    {
        int c0 = lane * 2;
        float w0 = n2w[c0], w1 = n2w[c0 + 1];
        float b0 = n2b[c0], b1 = n2b[c0 + 1];
        #pragma unroll
        for (int it = 0; it < 8; it++) {
            int t = it * 8 + w;
            unsigned int pv = *(const unsigned int*)&ct[swz(t, c0, 136)];
            float v0 = b2f((ushort_t)(pv & 0xffff));
            float v1 = b2f((ushort_t)(pv >> 16));
            float s = v0 + v1, s2 = v0 * v0 + v1 * v1;
            #pragma unroll
            for (int off = 32; off; off >>= 1) {
                s  += __shfl_xor(s,  off, 64);
                s2 += __shfl_xor(s2, off, 64);
            }
            float mu   = s * (1.0f / 128.0f);
            float rstd = rsqrtf(s2 * (1.0f / 128.0f) - mu * mu + 1e-5f);
            float o0 = (v0 - mu) * rstd * w0 + b0;
            float o1 = (v1 - mu) * rstd * w1 + b1;
            *(unsigned int*)&x2out[(size_t)(t0 + t) * 128 + c0] = pv;
            unsigned int pk = (unsigned int)f2b(o0) | ((unsigned int)f2b(o1) << 16);
            *(unsigned int*)&ysout[(size_t)(t0 + t) * 128 + c0] = pk;
        }
    }
}

// ======== K3: fc1 + gelu + fc2 (h by 256-wide K-halves) + residual ==========
// 64 rows/block, 512 threads. LDS: ysT[64][136] + h[64][264] = 51200 B.
__global__ __launch_bounds__(512, 2) void k3_mlp(
    const ushort_t* __restrict__ ys, const ushort_t* __restrict__ fc1w,
    const float* __restrict__ fc1b, const ushort_t* __restrict__ fc2w,
    const float* __restrict__ fc2b, const ushort_t* __restrict__ x2,
    float* __restrict__ out)
{
    extern __shared__ ushort_t sm[];
    ushort_t* ysT = sm;           // [64][136] (swz)
    ushort_t* h   = sm + 8704;    // [64][264] (swz)

    int row0 = blockIdx.x * 64;
    int tid = threadIdx.x;
    int w = tid >> 6, lane = tid & 63;
    int quad = lane >> 4, lrow = lane & 15;

    #pragma unroll
    for (int it = 0; it < 2; it++) {
        int qd = it * 512 + tid;
        int r = qd >> 4, lq = qd & 15;
        *(uint4*)&ysT[swz(r, lq * 8, 136)] =
            *(const uint4*)&ys[(size_t)(row0 + r) * 128 + lq * 8];
    }
    __syncthreads();

    f4 acc2[4];
    #pragma unroll
    for (int i = 0; i < 4; i++) { f4 z = {0.f,0.f,0.f,0.f}; acc2[i] = z; }
    int n = w * 16 + lrow;

    for (int hh = 0; hh < 2; hh++) {
        // fc1: local N=256 (16 tiles, 2/wave), K=128
        f4 acc[4][2];
        #pragma unroll
        for (int i = 0; i < 4; i++)
            #pragma unroll
            for (int j = 0; j < 2; j++) { f4 z = {0.f,0.f,0.f,0.f}; acc[i][j] = z; }
        #pragma unroll
        for (int k0 = 0; k0 < 128; k0 += 32) {
            bf8 bv[2];
            #pragma unroll
            for (int jj = 0; jj < 2; jj++) {
                int frow = hh * 256 + (w * 2 + jj) * 16 + lrow;
                bv[jj] = *(const bf8*)&fc1w[(size_t)frow * 128 + k0 + quad * 8];
            }
            #pragma unroll
            for (int i = 0; i < 4; i++) {
                bf8 av = *(const bf8*)&ysT[swz(i * 16 + lrow, k0 + quad * 8, 136)];
                #pragma unroll
                for (int jj = 0; jj < 2; jj++)
                    acc[i][jj] = __builtin_amdgcn_mfma_f32_16x16x32_bf16(
                        av, bv[jj], acc[i][jj], 0, 0, 0);
            }
        }
        __syncthreads();   // prior fc2 done reading h before overwrite
        #pragma unroll
        for (int jj = 0; jj < 2; jj++) {
            int cb = (w * 2 + jj) * 16 + lrow;        // local col 0..255
            float bj = fc1b[hh * 256 + cb];
            #pragma unroll
            for (int i = 0; i < 4; i++) {
                #pragma unroll
                for (int r = 0; r < 4; r++) {
                    int row = i * 16 + quad * 4 + r;
                    h[swz(row, cb, 264)] = f2b(fast_gelu(acc[i][jj][r] + bj));
                }
            }
        }
        __syncthreads();
        // fc2 partial: K-half 256
        #pragma unroll
        for (int k0 = 0; k0 < 256; k0 += 32) {
            bf8 bv = *(const bf8*)&fc2w[(size_t)n * 512 + hh * 256 + k0 + quad * 8];
            #pragma unroll
            for (int i = 0; i < 4; i++) {
                bf8 av = *(const bf8*)&h[swz(i * 16 + lrow, k0 + quad * 8, 264)];
                acc2[i] = __builtin_amdgcn_mfma_f32_16x16x32_bf16(av, bv, acc2[i], 0, 0, 0);
            }
        }
    }

    float bj = fc2b[n];
    #pragma unroll
    for (int i = 0; i < 4; i++) {
        #pragma unroll
        for (int r = 0; r < 4; r++) {
            int grow = row0 + i * 16 + quad * 4 + r;
            out[(size_t)grow * 128 + n] =
                acc2[i][r] + bj + b2f(x2[(size_t)grow * 128 + n]);
        }
    }
}

extern "C" void kernel_launch(void* const* d_in, const int* in_sizes, int n_in,
                              void* d_out, int out_size, void* d_ws, size_t ws_size,
                              hipStream_t stream) {
    const float* x      = (const float*)d_in[0];
    const float* n1w    = (const float*)d_in[1];
    const float* n1b    = (const float*)d_in[2];
    const float* qkv_w  = (const float*)d_in[3];
    const float* qkv_b  = (const float*)d_in[4];
    const float* rpb    = (const float*)d_in[5];
    const float* proj_w = (const float*)d_in[6];
    const float* proj_b = (const float*)d_in[7];
    const float* n2w    = (const float*)d_in[8];
    const float* n2b    = (const float*)d_in[9];
    const float* fc1_w  = (const float*)d_in[10];
    const float* fc1_b  = (const float*)d_in[11];
    const float* fc2_w  = (const float*)d_in[12];
    const float* fc2_b  = (const float*)d_in[13];

    ushort_t* ws     = (ushort_t*)d_ws;
    ushort_t* params = ws;                    // [0, 262144)
    ushort_t* x2     = ws + 262144;           // 16.7M elems
    ushort_t* ysb    = ws + 17039360;         // 16.7M elems
    float*    outf   = (float*)d_out;

    cvt_params<<<(P_TOTAL + 255) / 256, 256, 0, stream>>>(
        qkv_w, qkv_b, proj_w, proj_b, fc1_w, fc1_b, fc2_w, fc2_b, params);

    k1_fused<<<MROWS / 64, 512, 80128, stream>>>(
        x, n1w, n1b, params + P_QKV_W, qkv_b, rpb,
        params + P_PROJ_W, proj_b, n2w, n2b, x2, ysb);

    k3_mlp<<<MROWS / 64, 512, 51200, stream>>>(
        ysb, params + P_FC1_W, fc1_b, params + P_FC2_W, fc2_b, x2, outf);
}